// Round 7
// baseline (475.676 us; speedup 1.0000x reference)
//
#include <hip/hip_runtime.h>
#include <hip/hip_cooperative_groups.h>
#include <math.h>

namespace cg = cooperative_groups;

// Problem constants: N=12000, NEI=32, K=8, D=64
#define NPTS 12000
#define NNEI 32
#define KK   8
#define DD   64
#define NBLK (NPTS / 16)   // 750 blocks x 512 threads, 16 points/block

// Round 7: single cooperative kernel, HIGH occupancy (750 blocks = ~3/CU,
// unlike round 4's 250 = 1/CU). Phase 0: blocks 0..7 pack W fragments to ws
// while ALL blocks run their prep (kmL, A-frags) -- overlapped. grid.sync.
// Phase A: MFMA -> xtr/dis -> softmax combine -> F (identical math to R6).
// grid.sync. Phase B: gather-aggregate 16 n's per block (2 per wave).
// Fallback: proven R6 3-kernel path if cooperative launch is rejected.

typedef __bf16 bf16x8 __attribute__((ext_vector_type(8)));
typedef float  f32x4  __attribute__((ext_vector_type(4)));

#define MFMA16(A, B, C) __builtin_amdgcn_mfma_f32_16x16x32_bf16((A), (B), (C), 0, 0, 0)

__device__ __forceinline__ void pack8(float4 u, float4 v, bf16x8& h, bf16x8& l) {
    float a[8] = {u.x, u.y, u.z, u.w, v.x, v.y, v.z, v.w};
    #pragma unroll
    for (int i = 0; i < 8; ++i) {
        __bf16 hh = (__bf16)a[i];
        h[i] = hh;
        l[i] = (__bf16)(a[i] - (float)hh);
    }
}

// ================= fused cooperative kernel (high-occupancy) =================
__launch_bounds__(512, 6)   // cap VGPR ~85 -> >=3 blocks/CU -> 768 slots >= 750
__global__ void fused2_kernel(const float* __restrict__ x,
                              const int*  __restrict__ nei,
                              const int*  __restrict__ mask,
                              const float* __restrict__ kp,
                              const float* __restrict__ W,
                              const float* __restrict__ b,
                              const float* __restrict__ scales,
                              bf16x8* __restrict__ Wpk,
                              float* __restrict__ F,
                              float* __restrict__ out) {
    __shared__ float xtr[KK][16][65];   // pad 65 -> conflict-free combine reads
    __shared__ float kmL[KK][DD];
    __shared__ float disl[16][12];

    const int t    = threadIdx.x;
    const int k    = t >> 6;            // wave index == kernel index
    const int lane = t & 63;
    const int c    = lane & 15;
    const int g    = lane >> 4;
    const int blk  = blockIdx.x;
    const int pbase = blk * 16;

    // ---- phase 0a (all blocks): prep kmL row + A-frags + scalars ----
    {
        float spv = (lane == 0) ? 0.f : kp[k * DD + lane];   // kp[:,0]==0
        float ss = spv * spv;
        #pragma unroll
        for (int off = 32; off > 0; off >>= 1) ss += __shfl_xor(ss, off);
        float nrm = sqrtf(fmaxf(ss, 1e-8f));
        float e  = __expf(nrm);
        float ei = 1.0f / e;
        float ch = 0.5f * (e + ei);
        float sh = 0.5f * (e - ei);
        kmL[k][lane] = (lane == 0) ? ch : -(sh / nrm) * spv;
    }
    const float es = __expf(scales[k]);
    float bnt[4];
    #pragma unroll
    for (int nt = 0; nt < 4; ++nt) bnt[nt] = b[k * DD + nt * 16 + c];

    bf16x8 Ah[2], Al[2];
    {
        const float* xr = x + (size_t)(pbase + c) * DD + g * 8;
        pack8(*(const float4*)(xr +  0), *(const float4*)(xr +  4), Ah[0], Al[0]);
        pack8(*(const float4*)(xr + 32), *(const float4*)(xr + 36), Ah[1], Al[1]);
    }

    // ---- phase 0b (blocks 0..7): pack W fragments to workspace ----
    if (blk < 8) {
        const int id   = blk * 512 + t;     // 0..4095
        const int ln2  = id & 63;
        const int ks2  = (id >> 6) & 1;
        const int nt2  = (id >> 7) & 3;
        const int k2   = id >> 9;
        const int c2   = ln2 & 15;
        const int g2   = ln2 >> 4;
        const float* wr = W + ((size_t)k2 * DD + nt2 * 16 + c2) * DD + ks2 * 32 + g2 * 8;
        bf16x8 h, l;
        pack8(*(const float4*)wr, *(const float4*)(wr + 4), h, l);
        const size_t base = ((((size_t)k2 * 4 + nt2) * 2 + ks2) * 2) * 64 + ln2;
        Wpk[base]      = h;
        Wpk[base + 64] = l;
    }

    __threadfence();
    cg::this_grid().sync();   // Wpk ready (and kmL via block barrier)

    // ---- W_k fragments: coalesced b128 loads from packed buffer ----
    bf16x8 Wh[4][2], Wl[4][2];
    #pragma unroll
    for (int nt = 0; nt < 4; ++nt)
        #pragma unroll
        for (int ks = 0; ks < 2; ++ks) {
            const size_t base = ((((size_t)k * 4 + nt) * 2 + ks) * 2) * 64 + lane;
            Wh[nt][ks] = Wpk[base];
            Wl[nt][ks] = Wpk[base + 64];
        }

    // km fragments from LDS (rows 8..15 zero)
    bf16x8 Mh[2], Ml[2];
    #pragma unroll
    for (int ks = 0; ks < 2; ++ks)
        #pragma unroll
        for (int j = 0; j < 8; ++j) {
            float v = (c < 8) ? kmL[c][ks * 32 + g * 8 + j] : 0.f;
            __bf16 hh = (__bf16)v;
            Mh[ks][j] = hh;
            Ml[ks][j] = (__bf16)(v - (float)hh);
        }

    // ---- MFMAs ----
    f32x4 accY[4];
    #pragma unroll
    for (int nt = 0; nt < 4; ++nt) accY[nt] = (f32x4){0.f, 0.f, 0.f, 0.f};
    f32x4 accI = (f32x4){0.f, 0.f, 0.f, 0.f};
    #pragma unroll
    for (int ks = 0; ks < 2; ++ks) {
        #pragma unroll
        for (int nt = 0; nt < 4; ++nt) {
            accY[nt] = MFMA16(Ah[ks], Wh[nt][ks], accY[nt]);
            accY[nt] = MFMA16(Ah[ks], Wl[nt][ks], accY[nt]);
            accY[nt] = MFMA16(Al[ks], Wh[nt][ks], accY[nt]);
        }
        accI = MFMA16(Ah[ks], Mh[ks], accI);
        accI = MFMA16(Ah[ks], Ml[ks], accI);
        accI = MFMA16(Al[ks], Mh[ks], accI);
    }

    // ---- epilogue: per-point stats (C layout: row p=g*4+rr, col o=nt*16+c) ----
    float yv[4][4], sall[4];
    #pragma unroll
    for (int rr = 0; rr < 4; ++rr) {
        float s = 0.f;
        #pragma unroll
        for (int nt = 0; nt < 4; ++nt) {
            float y = accY[nt][rr] + bnt[nt];
            yv[nt][rr] = y;
            s += y * y;
        }
        sall[rr] = s;
    }
    #pragma unroll
    for (int m = 1; m <= 8; m <<= 1)
        #pragma unroll
        for (int rr = 0; rr < 4; ++rr) sall[rr] += __shfl_xor(sall[rr], m);
    float y0[4];
    #pragma unroll
    for (int rr = 0; rr < 4; ++rr) y0[rr] = __shfl(yv[0][rr], lane & 48);

    #pragma unroll
    for (int rr = 0; rr < 4; ++rr) {
        const int p = g * 4 + rr;
        float nar2 = fmaxf(sall[rr] - y0[rr] * y0[rr], 1e-8f);
        float time = es / (1.0f + __expf(-y0[rr])) + 1.0001f;
        float s3   = sqrtf((time * time - 1.0f) / nar2);
        #pragma unroll
        for (int nt = 0; nt < 4; ++nt) {
            float v = yv[nt][rr] * s3;
            if (nt == 0 && c == 0) v = time;
            xtr[k][p][nt * 16 + c] = v;
        }
    }
    if (k == 0) {
        #pragma unroll
        for (int rr = 0; rr < 4; ++rr) {
            float nc  = fmaxf(accI[rr], 1.0f + 1e-7f);
            float dis = __logf(nc + sqrtf(nc * nc - 1.0f));  // arccosh
            if (c < 8) disl[g * 4 + rr][c] = dis;
        }
    }
    __syncthreads();

    // ---- combine: wave k handles points {2k, 2k+1} ----
    #pragma unroll
    for (int pi = 0; pi < 2; ++pi) {
        const int p = k * 2 + pi;
        float dk[KK];
        #pragma unroll
        for (int q = 0; q < KK; ++q) dk[q] = disl[p][q];
        float mx = -dk[0];
        #pragma unroll
        for (int q = 1; q < KK; ++q) mx = fmaxf(mx, -dk[q]);
        float wks[KK], sum = 0.f;
        #pragma unroll
        for (int q = 0; q < KK; ++q) { wks[q] = __expf(-dk[q] - mx); sum += wks[q]; }
        float inv = 1.0f / sum;
        float agg = 0.f;
        #pragma unroll
        for (int q = 0; q < KK; ++q) agg += wks[q] * inv * xtr[q][p][lane];

        float vv = (lane == 0) ? -agg * agg : agg * agg;
        #pragma unroll
        for (int m = 32; m > 0; m >>= 1) vv += __shfl_xor(vv, m);
        float den = sqrtf(fmaxf(fabsf(vv), 1e-8f));
        F[(size_t)(pbase + p) * DD + lane] = agg / den;
    }

    __threadfence();
    cg::this_grid().sync();   // F complete & visible across XCDs

    // ---- phase B: this block's 16 n's, 2 per wave ----
    const float4* F4 = (const float4*)F;
    #pragma unroll
    for (int i = 0; i < 2; ++i) {
        const int n = pbase + k * 2 + i;
        int vsrc;
        if (lane < 32) vsrc = nei[n * NNEI + lane];
        else           vsrc = mask[n * NNEI + (lane - 32)];

        float4 acc = {0.f, 0.f, 0.f, 0.f};
        #pragma unroll
        for (int mq = 0; mq < 8; ++mq) {
            int   m   = mq * 4 + g;
            int   j   = __shfl(vsrc, m);
            float wgt = (float)__shfl(vsrc, 32 + m) + 1e-4f;
            float4 v  = F4[(size_t)j * 16 + c];
            acc.x += wgt * v.x; acc.y += wgt * v.y;
            acc.z += wgt * v.z; acc.w += wgt * v.w;
        }
        #pragma unroll
        for (int m = 16; m <= 32; m <<= 1) {
            acc.x += __shfl_xor(acc.x, m); acc.y += __shfl_xor(acc.y, m);
            acc.z += __shfl_xor(acc.z, m); acc.w += __shfl_xor(acc.w, m);
        }
        float s = acc.x * acc.x + acc.y * acc.y + acc.z * acc.z + acc.w * acc.w;
        if (c == 0) s -= 2.0f * acc.x * acc.x;
        #pragma unroll
        for (int m = 1; m <= 8; m <<= 1) s += __shfl_xor(s, m);
        float den = sqrtf(fmaxf(fabsf(s), 1e-8f));
        if (g == 0) {
            float4 rr = {acc.x / den, acc.y / den, acc.z / den, acc.w / den};
            ((float4*)out)[(size_t)n * 16 + c] = rr;
        }
    }
}

// ================= fallback path: proven round-6 3-kernel pipeline =================
__launch_bounds__(512)
__global__ void packW_kernel(const float* __restrict__ W,
                             bf16x8* __restrict__ Wpk) {
    const int id   = blockIdx.x * 512 + threadIdx.x;   // 0..4095
    const int lane = id & 63;
    const int ks   = (id >> 6) & 1;
    const int nt   = (id >> 7) & 3;
    const int k    = id >> 9;
    const int c    = lane & 15;
    const int g    = lane >> 4;
    const float* wr = W + ((size_t)k * DD + nt * 16 + c) * DD + ks * 32 + g * 8;
    bf16x8 h, l;
    pack8(*(const float4*)wr, *(const float4*)(wr + 4), h, l);
    const size_t base = ((((size_t)k * 4 + nt) * 2 + ks) * 2) * 64 + lane;
    Wpk[base]      = h;
    Wpk[base + 64] = l;
}

__launch_bounds__(512)
__global__ void passA_kernel(const float* __restrict__ x,
                             const float* __restrict__ kp,
                             const bf16x8* __restrict__ Wpk,
                             const float* __restrict__ b,
                             const float* __restrict__ scales,
                             float* __restrict__ F) {
    __shared__ float xtr[KK][16][65];
    __shared__ float kmL[KK][DD];
    __shared__ float disl[16][12];
    const int t = threadIdx.x, k = t >> 6, lane = t & 63, c = lane & 15, g = lane >> 4;
    const int pbase = blockIdx.x * 16;
    {
        float spv = (lane == 0) ? 0.f : kp[k * DD + lane];
        float ss = spv * spv;
        #pragma unroll
        for (int off = 32; off > 0; off >>= 1) ss += __shfl_xor(ss, off);
        float nrm = sqrtf(fmaxf(ss, 1e-8f));
        float e = __expf(nrm), ei = 1.0f / e;
        kmL[k][lane] = (lane == 0) ? 0.5f * (e + ei) : -(0.5f * (e - ei) / nrm) * spv;
    }
    const float es = __expf(scales[k]);
    bf16x8 Wh[4][2], Wl[4][2];
    #pragma unroll
    for (int nt = 0; nt < 4; ++nt)
        #pragma unroll
        for (int ks = 0; ks < 2; ++ks) {
            const size_t base = ((((size_t)k * 4 + nt) * 2 + ks) * 2) * 64 + lane;
            Wh[nt][ks] = Wpk[base];
            Wl[nt][ks] = Wpk[base + 64];
        }
    float bnt[4];
    #pragma unroll
    for (int nt = 0; nt < 4; ++nt) bnt[nt] = b[k * DD + nt * 16 + c];
    bf16x8 Ah[2], Al[2];
    {
        const float* xr = x + (size_t)(pbase + c) * DD + g * 8;
        pack8(*(const float4*)(xr +  0), *(const float4*)(xr +  4), Ah[0], Al[0]);
        pack8(*(const float4*)(xr + 32), *(const float4*)(xr + 36), Ah[1], Al[1]);
    }
    __syncthreads();
    bf16x8 Mh[2], Ml[2];
    #pragma unroll
    for (int ks = 0; ks < 2; ++ks)
        #pragma unroll
        for (int j = 0; j < 8; ++j) {
            float v = (c < 8) ? kmL[c][ks * 32 + g * 8 + j] : 0.f;
            __bf16 hh = (__bf16)v;
            Mh[ks][j] = hh;
            Ml[ks][j] = (__bf16)(v - (float)hh);
        }
    f32x4 accY[4];
    #pragma unroll
    for (int nt = 0; nt < 4; ++nt) accY[nt] = (f32x4){0,0,0,0};
    f32x4 accI = (f32x4){0,0,0,0};
    #pragma unroll
    for (int ks = 0; ks < 2; ++ks) {
        #pragma unroll
        for (int nt = 0; nt < 4; ++nt) {
            accY[nt] = MFMA16(Ah[ks], Wh[nt][ks], accY[nt]);
            accY[nt] = MFMA16(Ah[ks], Wl[nt][ks], accY[nt]);
            accY[nt] = MFMA16(Al[ks], Wh[nt][ks], accY[nt]);
        }
        accI = MFMA16(Ah[ks], Mh[ks], accI);
        accI = MFMA16(Ah[ks], Ml[ks], accI);
        accI = MFMA16(Al[ks], Mh[ks], accI);
    }
    float yv[4][4], sall[4];
    #pragma unroll
    for (int rr = 0; rr < 4; ++rr) {
        float s = 0.f;
        #pragma unroll
        for (int nt = 0; nt < 4; ++nt) { float y = accY[nt][rr] + bnt[nt]; yv[nt][rr] = y; s += y * y; }
        sall[rr] = s;
    }
    #pragma unroll
    for (int m = 1; m <= 8; m <<= 1)
        #pragma unroll
        for (int rr = 0; rr < 4; ++rr) sall[rr] += __shfl_xor(sall[rr], m);
    float y0[4];
    #pragma unroll
    for (int rr = 0; rr < 4; ++rr) y0[rr] = __shfl(yv[0][rr], lane & 48);
    #pragma unroll
    for (int rr = 0; rr < 4; ++rr) {
        const int p = g * 4 + rr;
        float nar2 = fmaxf(sall[rr] - y0[rr] * y0[rr], 1e-8f);
        float time = es / (1.0f + __expf(-y0[rr])) + 1.0001f;
        float s3   = sqrtf((time * time - 1.0f) / nar2);
        #pragma unroll
        for (int nt = 0; nt < 4; ++nt) {
            float v = yv[nt][rr] * s3;
            if (nt == 0 && c == 0) v = time;
            xtr[k][p][nt * 16 + c] = v;
        }
    }
    if (k == 0) {
        #pragma unroll
        for (int rr = 0; rr < 4; ++rr) {
            float nc = fmaxf(accI[rr], 1.0f + 1e-7f);
            float dis = __logf(nc + sqrtf(nc * nc - 1.0f));
            if (c < 8) disl[g * 4 + rr][c] = dis;
        }
    }
    __syncthreads();
    #pragma unroll
    for (int pi = 0; pi < 2; ++pi) {
        const int p = k * 2 + pi;
        float dk[KK];
        #pragma unroll
        for (int q = 0; q < KK; ++q) dk[q] = disl[p][q];
        float mx = -dk[0];
        #pragma unroll
        for (int q = 1; q < KK; ++q) mx = fmaxf(mx, -dk[q]);
        float wks[KK], sum = 0.f;
        #pragma unroll
        for (int q = 0; q < KK; ++q) { wks[q] = __expf(-dk[q] - mx); sum += wks[q]; }
        float inv = 1.0f / sum;
        float agg = 0.f;
        #pragma unroll
        for (int q = 0; q < KK; ++q) agg += wks[q] * inv * xtr[q][p][lane];
        float vv = (lane == 0) ? -agg * agg : agg * agg;
        #pragma unroll
        for (int m = 32; m > 0; m >>= 1) vv += __shfl_xor(vv, m);
        float den = sqrtf(fmaxf(fabsf(vv), 1e-8f));
        F[(size_t)(pbase + p) * DD + lane] = agg / den;
    }
}

__launch_bounds__(256)
__global__ void passB_kernel(const float* __restrict__ F,
                             const int* __restrict__ nei,
                             const int* __restrict__ mask,
                             float* __restrict__ out) {
    const int t = threadIdx.x, wave = t >> 6, lane = t & 63, c = lane & 15, g = lane >> 4;
    const int n = blockIdx.x * 4 + wave;
    int vsrc;
    if (lane < 32) vsrc = nei[n * NNEI + lane];
    else           vsrc = mask[n * NNEI + (lane - 32)];
    const float4* F4 = (const float4*)F;
    float4 acc = {0,0,0,0};
    #pragma unroll
    for (int mq = 0; mq < 8; ++mq) {
        int m = mq * 4 + g;
        int j = __shfl(vsrc, m);
        float wgt = (float)__shfl(vsrc, 32 + m) + 1e-4f;
        float4 v = F4[(size_t)j * 16 + c];
        acc.x += wgt * v.x; acc.y += wgt * v.y; acc.z += wgt * v.z; acc.w += wgt * v.w;
    }
    #pragma unroll
    for (int m = 16; m <= 32; m <<= 1) {
        acc.x += __shfl_xor(acc.x, m); acc.y += __shfl_xor(acc.y, m);
        acc.z += __shfl_xor(acc.z, m); acc.w += __shfl_xor(acc.w, m);
    }
    float s = acc.x * acc.x + acc.y * acc.y + acc.z * acc.z + acc.w * acc.w;
    if (c == 0) s -= 2.0f * acc.x * acc.x;
    #pragma unroll
    for (int m = 1; m <= 8; m <<= 1) s += __shfl_xor(s, m);
    float den = sqrtf(fmaxf(fabsf(s), 1e-8f));
    if (g == 0) {
        float4 rr = {acc.x / den, acc.y / den, acc.z / den, acc.w / den};
        ((float4*)out)[(size_t)n * 16 + c] = rr;
    }
}

// ---------------------------------------------------------------- launch ---
extern "C" void kernel_launch(void* const* d_in, const int* in_sizes, int n_in,
                              void* d_out, int out_size, void* d_ws, size_t ws_size,
                              hipStream_t stream) {
    const float* x      = (const float*)d_in[0];  // (12000, 64) f32
    const int*   nei    = (const int*)  d_in[1];  // (12000, 32) int32
    const int*   mask   = (const int*)  d_in[2];  // (12000, 32) int32
    const float* kp     = (const float*)d_in[3];  // (8, 64) f32
    const float* W      = (const float*)d_in[4];  // (8, 64, 64) f32
    const float* b      = (const float*)d_in[5];  // (8, 64) f32
    const float* scales = (const float*)d_in[6];  // (8,) f32
    float*       out    = (float*)d_out;          // (12000, 64) f32

    // ws: [0, N*D) F (f32) ; then Wpk: 8192 bf16x8 entries (128 KB, 16B-aligned)
    const size_t needed = (size_t)(NPTS * DD) * sizeof(float) + 8192 * 16;
    if (ws_size < needed) return;
    float*  F   = (float*)d_ws;
    bf16x8* Wpk = (bf16x8*)(F + (size_t)NPTS * DD);

    void* args[10] = {(void*)&x, (void*)&nei, (void*)&mask, (void*)&kp, (void*)&W,
                      (void*)&b, (void*)&scales, (void*)&Wpk, (void*)&F, (void*)&out};
    hipError_t err = hipLaunchCooperativeKernel((const void*)fused2_kernel,
                                                dim3(NBLK), dim3(512),
                                                (void**)args, 0, stream);
    if (err != hipSuccess) {
        packW_kernel<<<8, 512, 0, stream>>>(W, Wpk);
        passA_kernel<<<NPTS / 16, 512, 0, stream>>>(x, kp, Wpk, b, scales, F);
        passB_kernel<<<NPTS / 4, 256, 0, stream>>>(F, nei, mask, out);
    }
}

// Round 8
// 72.296 us; speedup vs baseline: 6.5795x; 6.5795x over previous
//
#include <hip/hip_runtime.h>
#include <math.h>

// Problem constants: N=12000, NEI=32, K=8, D=64
#define NPTS 12000
#define NNEI 32
#define KK   8
#define DD   64

// Round 8: MEASUREMENT ROUND. Identical pipeline to round 6 (34.1 us,
// proven), except passA repeats its full body REPS=3 times (same outputs,
// deterministic). Purpose: (1) marginal cost of passA = (total-34.1)/2,
// (2) if passA*3 > ~42us it enters rocprof top-5 over the 40us poison
// fills, giving direct MfmaUtil/VALUBusy/FETCH counters for passA.
// Pointers are laundered through empty asm per rep so the compiler cannot
// hoist the loop-invariant computation (inputs never change across reps).

#define REPS 3

typedef __bf16 bf16x8 __attribute__((ext_vector_type(8)));
typedef float  f32x4  __attribute__((ext_vector_type(4)));

#define MFMA16(A, B, C) __builtin_amdgcn_mfma_f32_16x16x32_bf16((A), (B), (C), 0, 0, 0)

__device__ __forceinline__ void pack8(float4 u, float4 v, bf16x8& h, bf16x8& l) {
    float a[8] = {u.x, u.y, u.z, u.w, v.x, v.y, v.z, v.w};
    #pragma unroll
    for (int i = 0; i < 8; ++i) {
        __bf16 hh = (__bf16)a[i];
        h[i] = hh;
        l[i] = (__bf16)(a[i] - (float)hh);
    }
}

template <typename T>
__device__ __forceinline__ T* launder_ptr(T* p) {
    asm volatile("" : "+v"(p));   // opaque: defeats hoist/CSE across reps
    return p;
}

// ---------------------------------------------------------------- packW ----
__launch_bounds__(512)
__global__ void packW_kernel(const float* __restrict__ W,
                             bf16x8* __restrict__ Wpk) {
    const int id   = blockIdx.x * 512 + threadIdx.x;   // 0..4095
    const int lane = id & 63;
    const int ks   = (id >> 6) & 1;
    const int nt   = (id >> 7) & 3;
    const int k    = id >> 9;
    const int c    = lane & 15;
    const int g    = lane >> 4;

    const float* wr = W + ((size_t)k * DD + nt * 16 + c) * DD + ks * 32 + g * 8;
    bf16x8 h, l;
    pack8(*(const float4*)wr, *(const float4*)(wr + 4), h, l);
    const size_t base = ((((size_t)k * 4 + nt) * 2 + ks) * 2) * 64 + lane;
    Wpk[base]      = h;   // hi plane
    Wpk[base + 64] = l;   // lo plane
}

// ---------------------------------------------------------------- pass A ---
__launch_bounds__(512)
__global__ void passA_kernel(const float* __restrict__ x0,
                             const float* __restrict__ kp0,
                             const bf16x8* __restrict__ Wpk0,
                             const float* __restrict__ b0,
                             const float* __restrict__ scales0,
                             float* __restrict__ F0) {
    __shared__ float xtr[KK][16][65];   // pad 65 -> conflict-free combine reads
    __shared__ float kmL[KK][DD];
    __shared__ float disl[16][12];

    const int t    = threadIdx.x;
    const int k    = t >> 6;            // wave index == kernel index
    const int lane = t & 63;
    const int c    = lane & 15;
    const int g    = lane >> 4;
    const int pbase = blockIdx.x * 16;

    for (int rep = 0; rep < REPS; ++rep) {
        // opaque per-rep views of the inputs (values identical every rep)
        const float*  x      = launder_ptr(x0);
        const float*  kp     = launder_ptr(kp0);
        const bf16x8* Wpk    = launder_ptr(Wpk0);
        const float*  b      = launder_ptr(b0);
        const float*  scales = launder_ptr(scales0);
        float*        F      = launder_ptr(F0);

        // ---- inline prep: km row for this wave's k (kernels*metric) ----
        {
            float spv = (lane == 0) ? 0.f : kp[k * DD + lane];   // kp[:,0]==0
            float ss = spv * spv;
            #pragma unroll
            for (int off = 32; off > 0; off >>= 1) ss += __shfl_xor(ss, off);
            float nrm = sqrtf(fmaxf(ss, 1e-8f));
            float e  = __expf(nrm);
            float ei = 1.0f / e;
            float ch = 0.5f * (e + ei);
            float sh = 0.5f * (e - ei);
            kmL[k][lane] = (lane == 0) ? ch : -(sh / nrm) * spv;
        }
        const float es = __expf(scales[k]);

        // ---- W_k fragments: coalesced b128 loads from pre-packed buffer ----
        bf16x8 Wh[4][2], Wl[4][2];
        #pragma unroll
        for (int nt = 0; nt < 4; ++nt)
            #pragma unroll
            for (int ks = 0; ks < 2; ++ks) {
                const size_t base = ((((size_t)k * 4 + nt) * 2 + ks) * 2) * 64 + lane;
                Wh[nt][ks] = Wpk[base];
                Wl[nt][ks] = Wpk[base + 64];
            }
        float bnt[4];
        #pragma unroll
        for (int nt = 0; nt < 4; ++nt) bnt[nt] = b[k * DD + nt * 16 + c];

        // ---- A fragments: this block's 16 x-rows ----
        bf16x8 Ah[2], Al[2];
        {
            const float* xr = x + (size_t)(pbase + c) * DD + g * 8;
            pack8(*(const float4*)(xr +  0), *(const float4*)(xr +  4), Ah[0], Al[0]);
            pack8(*(const float4*)(xr + 32), *(const float4*)(xr + 36), Ah[1], Al[1]);
        }

        __syncthreads();  // kmL ready

        // km fragments from LDS (rows 8..15 zero)
        bf16x8 Mh[2], Ml[2];
        #pragma unroll
        for (int ks = 0; ks < 2; ++ks)
            #pragma unroll
            for (int j = 0; j < 8; ++j) {
                float v = (c < 8) ? kmL[c][ks * 32 + g * 8 + j] : 0.f;
                __bf16 hh = (__bf16)v;
                Mh[ks][j] = hh;
                Ml[ks][j] = (__bf16)(v - (float)hh);
            }

        // ---- MFMAs ----
        f32x4 accY[4];
        #pragma unroll
        for (int nt = 0; nt < 4; ++nt) accY[nt] = (f32x4){0.f, 0.f, 0.f, 0.f};
        f32x4 accI = (f32x4){0.f, 0.f, 0.f, 0.f};
        #pragma unroll
        for (int ks = 0; ks < 2; ++ks) {
            #pragma unroll
            for (int nt = 0; nt < 4; ++nt) {
                accY[nt] = MFMA16(Ah[ks], Wh[nt][ks], accY[nt]);
                accY[nt] = MFMA16(Ah[ks], Wl[nt][ks], accY[nt]);
                accY[nt] = MFMA16(Al[ks], Wh[nt][ks], accY[nt]);
            }
            accI = MFMA16(Ah[ks], Mh[ks], accI);
            accI = MFMA16(Ah[ks], Ml[ks], accI);
            accI = MFMA16(Al[ks], Mh[ks], accI);
        }

        // ---- epilogue: per-point stats (C layout: row p=g*4+rr, col o=nt*16+c) ----
        float yv[4][4], sall[4];
        #pragma unroll
        for (int rr = 0; rr < 4; ++rr) {
            float s = 0.f;
            #pragma unroll
            for (int nt = 0; nt < 4; ++nt) {
                float y = accY[nt][rr] + bnt[nt];
                yv[nt][rr] = y;
                s += y * y;
            }
            sall[rr] = s;
        }
        #pragma unroll
        for (int m = 1; m <= 8; m <<= 1)
            #pragma unroll
            for (int rr = 0; rr < 4; ++rr) sall[rr] += __shfl_xor(sall[rr], m);
        float y0[4];
        #pragma unroll
        for (int rr = 0; rr < 4; ++rr) y0[rr] = __shfl(yv[0][rr], lane & 48);

        #pragma unroll
        for (int rr = 0; rr < 4; ++rr) {
            const int p = g * 4 + rr;
            float nar2 = fmaxf(sall[rr] - y0[rr] * y0[rr], 1e-8f);
            float time = es / (1.0f + __expf(-y0[rr])) + 1.0001f;
            float s3   = sqrtf((time * time - 1.0f) / nar2);
            #pragma unroll
            for (int nt = 0; nt < 4; ++nt) {
                float v = yv[nt][rr] * s3;
                if (nt == 0 && c == 0) v = time;
                xtr[k][p][nt * 16 + c] = v;
            }
        }
        if (k == 0) {
            #pragma unroll
            for (int rr = 0; rr < 4; ++rr) {
                float nc  = fmaxf(accI[rr], 1.0f + 1e-7f);
                float dis = __logf(nc + sqrtf(nc * nc - 1.0f));  // arccosh
                if (c < 8) disl[g * 4 + rr][c] = dis;
            }
        }
        __syncthreads();

        // ---- combine: wave k handles points {2k, 2k+1} ----
        #pragma unroll
        for (int pi = 0; pi < 2; ++pi) {
            const int p = k * 2 + pi;
            float dk[KK];
            #pragma unroll
            for (int q = 0; q < KK; ++q) dk[q] = disl[p][q];
            float mx = -dk[0];
            #pragma unroll
            for (int q = 1; q < KK; ++q) mx = fmaxf(mx, -dk[q]);
            float wks[KK], sum = 0.f;
            #pragma unroll
            for (int q = 0; q < KK; ++q) { wks[q] = __expf(-dk[q] - mx); sum += wks[q]; }
            float inv = 1.0f / sum;
            float agg = 0.f;
            #pragma unroll
            for (int q = 0; q < KK; ++q) agg += wks[q] * inv * xtr[q][p][lane];

            float vv = (lane == 0) ? -agg * agg : agg * agg;
            #pragma unroll
            for (int m = 32; m > 0; m >>= 1) vv += __shfl_xor(vv, m);
            float den = sqrtf(fmaxf(fabsf(vv), 1e-8f));
            F[(size_t)(pbase + p) * DD + lane] = agg / den;
        }
        __syncthreads();  // xtr/disl/kmL safe to rewrite next rep
    }
}

// ---------------------------------------------------------------- pass B ---
__launch_bounds__(256)
__global__ void passB_kernel(const float* __restrict__ F,
                             const int* __restrict__ nei,
                             const int* __restrict__ mask,
                             float* __restrict__ out) {
    const int t    = threadIdx.x;
    const int wave = t >> 6;
    const int lane = t & 63;
    const int c    = lane & 15;   // col quad: o = 4c..4c+3
    const int g    = lane >> 4;   // m sub-index
    const int n    = blockIdx.x * 4 + wave;

    // one coalesced 256B fetch per wave: lanes 0..31 nei row, 32..63 mask row
    int vsrc;
    if (lane < 32) vsrc = nei[n * NNEI + lane];
    else           vsrc = mask[n * NNEI + (lane - 32)];

    const float4* F4 = (const float4*)F;
    float4 acc = {0.f, 0.f, 0.f, 0.f};
    #pragma unroll
    for (int mq = 0; mq < 8; ++mq) {
        int   m   = mq * 4 + g;
        int   j   = __shfl(vsrc, m);
        float wgt = (float)__shfl(vsrc, 32 + m) + 1e-4f;
        float4 v  = F4[(size_t)j * 16 + c];
        acc.x += wgt * v.x; acc.y += wgt * v.y;
        acc.z += wgt * v.z; acc.w += wgt * v.w;
    }
    // reduce over the 4 m-subgroups (lanes xor 16, 32)
    #pragma unroll
    for (int m = 16; m <= 32; m <<= 1) {
        acc.x += __shfl_xor(acc.x, m); acc.y += __shfl_xor(acc.y, m);
        acc.z += __shfl_xor(acc.z, m); acc.w += __shfl_xor(acc.w, m);
    }
    // lorentz inner: minus sign on o==0 (lane c==0, component .x)
    float s = acc.x * acc.x + acc.y * acc.y + acc.z * acc.z + acc.w * acc.w;
    if (c == 0) s -= 2.0f * acc.x * acc.x;
    #pragma unroll
    for (int m = 1; m <= 8; m <<= 1) s += __shfl_xor(s, m);
    float den = sqrtf(fmaxf(fabsf(s), 1e-8f));
    if (g == 0) {
        float4 rr = {acc.x / den, acc.y / den, acc.z / den, acc.w / den};
        ((float4*)out)[(size_t)n * 16 + c] = rr;
    }
}

// ---------------------------------------------------------------- launch ---
extern "C" void kernel_launch(void* const* d_in, const int* in_sizes, int n_in,
                              void* d_out, int out_size, void* d_ws, size_t ws_size,
                              hipStream_t stream) {
    const float* x      = (const float*)d_in[0];  // (12000, 64) f32
    const int*   nei    = (const int*)  d_in[1];  // (12000, 32) int32
    const int*   mask   = (const int*)  d_in[2];  // (12000, 32) int32
    const float* kp     = (const float*)d_in[3];  // (8, 64) f32
    const float* W      = (const float*)d_in[4];  // (8, 64, 64) f32
    const float* b      = (const float*)d_in[5];  // (8, 64) f32
    const float* scales = (const float*)d_in[6];  // (8,) f32
    float*       out    = (float*)d_out;          // (12000, 64) f32

    // ws: [0, N*D) F (f32) ; then Wpk: 8192 bf16x8 entries (128 KB, 16B-aligned)
    const size_t needed = (size_t)(NPTS * DD) * sizeof(float) + 8192 * 16;
    if (ws_size < needed) return;
    float*  F   = (float*)d_ws;
    bf16x8* Wpk = (bf16x8*)(F + (size_t)NPTS * DD);

    packW_kernel<<<8, 512, 0, stream>>>(W, Wpk);
    passA_kernel<<<NPTS / 16, 512, 0, stream>>>(x, kp, Wpk, b, scales, F);
    passB_kernel<<<NPTS / 4, 256, 0, stream>>>(F, nei, mask, out);
}

// Round 9
// 39.232 us; speedup vs baseline: 12.1247x; 1.8428x over previous
//
#include <hip/hip_runtime.h>
#include <math.h>

// Problem constants: N=12000, NEI=32, K=8, D=64
#define NPTS 12000
#define NNEI 32
#define KK   8
#define DD   64

// Round 9 (from R8 measurement: passA=19.9us, VALUBusy 36%, MfmaUtil 5.6%,
// 1.5M LDS conflict-cycles, occupancy 19%):
//  1. 32 points/block (2 MFMA rounds), grid 375: halves the number of
//     per-block prologues (kmL chain + 16 Wpk loads + Mh/Ml ~200 VALU + L2
//     latency), which R8 showed cannot be hidden at 16 pts/block.
//  2. xtr row stride 65 -> 68: write bank = c + 16*(g&1) (2-way, free)
//     instead of (4g+c) mod 32 (4-way). Combine read stays lane-linear.
//  3. REPS/launder instrumentation removed.

#define RNDS  2
#define PTSB  (16 * RNDS)      // 32 points per block
#define NBLKA (NPTS / PTSB)    // 375

typedef __bf16 bf16x8 __attribute__((ext_vector_type(8)));
typedef float  f32x4  __attribute__((ext_vector_type(4)));

#define MFMA16(A, B, C) __builtin_amdgcn_mfma_f32_16x16x32_bf16((A), (B), (C), 0, 0, 0)

__device__ __forceinline__ void pack8(float4 u, float4 v, bf16x8& h, bf16x8& l) {
    float a[8] = {u.x, u.y, u.z, u.w, v.x, v.y, v.z, v.w};
    #pragma unroll
    for (int i = 0; i < 8; ++i) {
        __bf16 hh = (__bf16)a[i];
        h[i] = hh;
        l[i] = (__bf16)(a[i] - (float)hh);
    }
}

// ---------------------------------------------------------------- packW ----
__launch_bounds__(512)
__global__ void packW_kernel(const float* __restrict__ W,
                             bf16x8* __restrict__ Wpk) {
    const int id   = blockIdx.x * 512 + threadIdx.x;   // 0..4095
    const int lane = id & 63;
    const int ks   = (id >> 6) & 1;
    const int nt   = (id >> 7) & 3;
    const int k    = id >> 9;
    const int c    = lane & 15;
    const int g    = lane >> 4;

    const float* wr = W + ((size_t)k * DD + nt * 16 + c) * DD + ks * 32 + g * 8;
    bf16x8 h, l;
    pack8(*(const float4*)wr, *(const float4*)(wr + 4), h, l);
    const size_t base = ((((size_t)k * 4 + nt) * 2 + ks) * 2) * 64 + lane;
    Wpk[base]      = h;   // hi plane
    Wpk[base + 64] = l;   // lo plane
}

// ---------------------------------------------------------------- pass A ---
__launch_bounds__(512)
__global__ void passA_kernel(const float* __restrict__ x,
                             const float* __restrict__ kp,
                             const bf16x8* __restrict__ Wpk,
                             const float* __restrict__ b,
                             const float* __restrict__ scales,
                             float* __restrict__ F) {
    __shared__ float xtr[KK][16][68];   // stride 68: write bank = c+16*(g&1) -> 2-way free
    __shared__ float kmL[KK][DD];
    __shared__ float disl[16][12];

    const int t    = threadIdx.x;
    const int k    = t >> 6;            // wave index == kernel index
    const int lane = t & 63;
    const int c    = lane & 15;
    const int g    = lane >> 4;

    // ======== prologue (once per block, amortized over 32 points) ========
    // km row for this wave's k (kernels*metric)
    {
        float spv = (lane == 0) ? 0.f : kp[k * DD + lane];   // kp[:,0]==0
        float ss = spv * spv;
        #pragma unroll
        for (int off = 32; off > 0; off >>= 1) ss += __shfl_xor(ss, off);
        float nrm = sqrtf(fmaxf(ss, 1e-8f));
        float e  = __expf(nrm);
        float ei = 1.0f / e;
        float ch = 0.5f * (e + ei);
        float sh = 0.5f * (e - ei);
        kmL[k][lane] = (lane == 0) ? ch : -(sh / nrm) * spv;
    }
    const float es = __expf(scales[k]);

    // W_k fragments: coalesced b128 loads from pre-packed buffer
    bf16x8 Wh[4][2], Wl[4][2];
    #pragma unroll
    for (int nt = 0; nt < 4; ++nt)
        #pragma unroll
        for (int ks = 0; ks < 2; ++ks) {
            const size_t base = ((((size_t)k * 4 + nt) * 2 + ks) * 2) * 64 + lane;
            Wh[nt][ks] = Wpk[base];
            Wl[nt][ks] = Wpk[base + 64];
        }
    float bnt[4];
    #pragma unroll
    for (int nt = 0; nt < 4; ++nt) bnt[nt] = b[k * DD + nt * 16 + c];

    __syncthreads();  // kmL ready

    // km fragments from LDS (rows 8..15 zero)
    bf16x8 Mh[2], Ml[2];
    #pragma unroll
    for (int ks = 0; ks < 2; ++ks)
        #pragma unroll
        for (int j = 0; j < 8; ++j) {
            float v = (c < 8) ? kmL[c][ks * 32 + g * 8 + j] : 0.f;
            __bf16 hh = (__bf16)v;
            Mh[ks][j] = hh;
            Ml[ks][j] = (__bf16)(v - (float)hh);
        }

    // ======== 2 rounds of 16 points ========
    for (int r = 0; r < RNDS; ++r) {
        const int pbase = blockIdx.x * PTSB + r * 16;

        // A fragments: this round's 16 x-rows
        bf16x8 Ah[2], Al[2];
        {
            const float* xr = x + (size_t)(pbase + c) * DD + g * 8;
            pack8(*(const float4*)(xr +  0), *(const float4*)(xr +  4), Ah[0], Al[0]);
            pack8(*(const float4*)(xr + 32), *(const float4*)(xr + 36), Ah[1], Al[1]);
        }

        // MFMAs
        f32x4 accY[4];
        #pragma unroll
        for (int nt = 0; nt < 4; ++nt) accY[nt] = (f32x4){0.f, 0.f, 0.f, 0.f};
        f32x4 accI = (f32x4){0.f, 0.f, 0.f, 0.f};
        #pragma unroll
        for (int ks = 0; ks < 2; ++ks) {
            #pragma unroll
            for (int nt = 0; nt < 4; ++nt) {
                accY[nt] = MFMA16(Ah[ks], Wh[nt][ks], accY[nt]);
                accY[nt] = MFMA16(Ah[ks], Wl[nt][ks], accY[nt]);
                accY[nt] = MFMA16(Al[ks], Wh[nt][ks], accY[nt]);
            }
            accI = MFMA16(Ah[ks], Mh[ks], accI);
            accI = MFMA16(Ah[ks], Ml[ks], accI);
            accI = MFMA16(Al[ks], Mh[ks], accI);
        }

        // epilogue: per-point stats (C layout: row p=g*4+rr, col o=nt*16+c)
        float yv[4][4], sall[4];
        #pragma unroll
        for (int rr = 0; rr < 4; ++rr) {
            float s = 0.f;
            #pragma unroll
            for (int nt = 0; nt < 4; ++nt) {
                float y = accY[nt][rr] + bnt[nt];
                yv[nt][rr] = y;
                s += y * y;
            }
            sall[rr] = s;
        }
        #pragma unroll
        for (int m = 1; m <= 8; m <<= 1)
            #pragma unroll
            for (int rr = 0; rr < 4; ++rr) sall[rr] += __shfl_xor(sall[rr], m);
        float y0[4];
        #pragma unroll
        for (int rr = 0; rr < 4; ++rr) y0[rr] = __shfl(yv[0][rr], lane & 48);

        #pragma unroll
        for (int rr = 0; rr < 4; ++rr) {
            const int p = g * 4 + rr;
            float nar2 = fmaxf(sall[rr] - y0[rr] * y0[rr], 1e-8f);
            float time = es / (1.0f + __expf(-y0[rr])) + 1.0001f;
            float s3   = sqrtf((time * time - 1.0f) / nar2);
            #pragma unroll
            for (int nt = 0; nt < 4; ++nt) {
                float v = yv[nt][rr] * s3;
                if (nt == 0 && c == 0) v = time;
                xtr[k][p][nt * 16 + c] = v;
            }
        }
        if (k == 0) {
            #pragma unroll
            for (int rr = 0; rr < 4; ++rr) {
                float nc  = fmaxf(accI[rr], 1.0f + 1e-7f);
                float dis = __logf(nc + sqrtf(nc * nc - 1.0f));  // arccosh
                if (c < 8) disl[g * 4 + rr][c] = dis;
            }
        }
        __syncthreads();

        // combine: wave k handles points {2k, 2k+1}
        #pragma unroll
        for (int pi = 0; pi < 2; ++pi) {
            const int p = k * 2 + pi;
            float dk[KK];
            #pragma unroll
            for (int q = 0; q < KK; ++q) dk[q] = disl[p][q];
            float mx = -dk[0];
            #pragma unroll
            for (int q = 1; q < KK; ++q) mx = fmaxf(mx, -dk[q]);
            float wks[KK], sum = 0.f;
            #pragma unroll
            for (int q = 0; q < KK; ++q) { wks[q] = __expf(-dk[q] - mx); sum += wks[q]; }
            float inv = 1.0f / sum;
            float agg = 0.f;
            #pragma unroll
            for (int q = 0; q < KK; ++q) agg += wks[q] * inv * xtr[q][p][lane];

            float vv = (lane == 0) ? -agg * agg : agg * agg;
            #pragma unroll
            for (int m = 32; m > 0; m >>= 1) vv += __shfl_xor(vv, m);
            float den = sqrtf(fmaxf(fabsf(vv), 1e-8f));
            F[(size_t)(pbase + p) * DD + lane] = agg / den;
        }
        if (r + 1 < RNDS) __syncthreads();   // xtr/disl rewritten next round
    }
}

// ---------------------------------------------------------------- pass B ---
__launch_bounds__(256)
__global__ void passB_kernel(const float* __restrict__ F,
                             const int* __restrict__ nei,
                             const int* __restrict__ mask,
                             float* __restrict__ out) {
    const int t    = threadIdx.x;
    const int wave = t >> 6;
    const int lane = t & 63;
    const int c    = lane & 15;   // col quad: o = 4c..4c+3
    const int g    = lane >> 4;   // m sub-index
    const int n    = blockIdx.x * 4 + wave;

    // one coalesced 256B fetch per wave: lanes 0..31 nei row, 32..63 mask row
    int vsrc;
    if (lane < 32) vsrc = nei[n * NNEI + lane];
    else           vsrc = mask[n * NNEI + (lane - 32)];

    const float4* F4 = (const float4*)F;
    float4 acc = {0.f, 0.f, 0.f, 0.f};
    #pragma unroll
    for (int mq = 0; mq < 8; ++mq) {
        int   m   = mq * 4 + g;
        int   j   = __shfl(vsrc, m);
        float wgt = (float)__shfl(vsrc, 32 + m) + 1e-4f;
        float4 v  = F4[(size_t)j * 16 + c];
        acc.x += wgt * v.x; acc.y += wgt * v.y;
        acc.z += wgt * v.z; acc.w += wgt * v.w;
    }
    // reduce over the 4 m-subgroups (lanes xor 16, 32)
    #pragma unroll
    for (int m = 16; m <= 32; m <<= 1) {
        acc.x += __shfl_xor(acc.x, m); acc.y += __shfl_xor(acc.y, m);
        acc.z += __shfl_xor(acc.z, m); acc.w += __shfl_xor(acc.w, m);
    }
    // lorentz inner: minus sign on o==0 (lane c==0, component .x)
    float s = acc.x * acc.x + acc.y * acc.y + acc.z * acc.z + acc.w * acc.w;
    if (c == 0) s -= 2.0f * acc.x * acc.x;
    #pragma unroll
    for (int m = 1; m <= 8; m <<= 1) s += __shfl_xor(s, m);
    float den = sqrtf(fmaxf(fabsf(s), 1e-8f));
    if (g == 0) {
        float4 rr = {acc.x / den, acc.y / den, acc.z / den, acc.w / den};
        ((float4*)out)[(size_t)n * 16 + c] = rr;
    }
}

// ---------------------------------------------------------------- launch ---
extern "C" void kernel_launch(void* const* d_in, const int* in_sizes, int n_in,
                              void* d_out, int out_size, void* d_ws, size_t ws_size,
                              hipStream_t stream) {
    const float* x      = (const float*)d_in[0];  // (12000, 64) f32
    const int*   nei    = (const int*)  d_in[1];  // (12000, 32) int32
    const int*   mask   = (const int*)  d_in[2];  // (12000, 32) int32
    const float* kp     = (const float*)d_in[3];  // (8, 64) f32
    const float* W      = (const float*)d_in[4];  // (8, 64, 64) f32
    const float* b      = (const float*)d_in[5];  // (8, 64) f32
    const float* scales = (const float*)d_in[6];  // (8,) f32
    float*       out    = (float*)d_out;          // (12000, 64) f32

    // ws: [0, N*D) F (f32) ; then Wpk: 8192 bf16x8 entries (128 KB, 16B-aligned)
    const size_t needed = (size_t)(NPTS * DD) * sizeof(float) + 8192 * 16;
    if (ws_size < needed) return;
    float*  F   = (float*)d_ws;
    bf16x8* Wpk = (bf16x8*)(F + (size_t)NPTS * DD);

    packW_kernel<<<8, 512, 0, stream>>>(W, Wpk);
    passA_kernel<<<NBLKA, 512, 0, stream>>>(x, kp, Wpk, b, scales, F);
    passB_kernel<<<NPTS / 4, 256, 0, stream>>>(F, nei, mask, out);
}

// Round 10
// 32.789 us; speedup vs baseline: 14.5070x; 1.1965x over previous
//
#include <hip/hip_runtime.h>
#include <math.h>

// Problem constants: N=12000, NEI=32, K=8, D=64
#define NPTS 12000
#define NNEI 32
#define KK   8
#define DD   64

// Round 10:
//  - Revert to R6's balanced grid: 750 blocks x 512 (16 pts/block). R9's
//    375-block layout was load-imbalanced (1.46 blocks/CU -> 73% util).
//  - Keep stride-68 xtr (write bank = c+16*((g+nt)&1), read 2-way: both free).
//  - Move ALL prologue compute into packW: block 0 additionally emits
//    pre-packed M-fragments (Mpk, 4KB) and exp(scales) (esA). passA's
//    prologue is now pure coalesced loads -- no km shuffle/cosh chain, no
//    Mh/Ml bf16-split VALU, no kmL LDS, one less __syncthreads.

typedef __bf16 bf16x8 __attribute__((ext_vector_type(8)));
typedef float  f32x4  __attribute__((ext_vector_type(4)));

#define MFMA16(A, B, C) __builtin_amdgcn_mfma_f32_16x16x32_bf16((A), (B), (C), 0, 0, 0)

__device__ __forceinline__ void pack8(float4 u, float4 v, bf16x8& h, bf16x8& l) {
    float a[8] = {u.x, u.y, u.z, u.w, v.x, v.y, v.z, v.w};
    #pragma unroll
    for (int i = 0; i < 8; ++i) {
        __bf16 hh = (__bf16)a[i];
        h[i] = hh;
        l[i] = (__bf16)(a[i] - (float)hh);
    }
}

// ---------------------------------------------------------------- packW ----
// 8 blocks x 512. Block b packs W fragments for kernel k=b. Block 0 also:
// km rows (kernels*metric) -> M-fragments Mpk, and esA[k]=exp(scales[k]).
__launch_bounds__(512)
__global__ void packW_kernel(const float* __restrict__ W,
                             const float* __restrict__ kp,
                             const float* __restrict__ scales,
                             bf16x8* __restrict__ Wpk,
                             bf16x8* __restrict__ Mpk,
                             float*  __restrict__ esA) {
    __shared__ float kmL[KK][DD];

    const int t    = threadIdx.x;
    const int id   = blockIdx.x * 512 + t;   // 0..4095
    const int lane = id & 63;
    const int ks   = (id >> 6) & 1;
    const int nt   = (id >> 7) & 3;
    const int k    = id >> 9;
    const int c    = lane & 15;
    const int g    = lane >> 4;

    // ---- W fragment pack (all 8 blocks) ----
    const float* wr = W + ((size_t)k * DD + nt * 16 + c) * DD + ks * 32 + g * 8;
    bf16x8 h, l;
    pack8(*(const float4*)wr, *(const float4*)(wr + 4), h, l);
    const size_t base = ((((size_t)k * 4 + nt) * 2 + ks) * 2) * 64 + lane;
    Wpk[base]      = h;   // hi plane
    Wpk[base + 64] = l;   // lo plane

    // ---- block 0: km rows + M fragments + esA ----
    if (blockIdx.x == 0) {
        const int w  = t >> 6;      // wave index = kernel row
        const int ln = t & 63;
        {
            float spv = (ln == 0) ? 0.f : kp[w * DD + ln];   // kp[:,0]==0
            float ss = spv * spv;
            #pragma unroll
            for (int off = 32; off > 0; off >>= 1) ss += __shfl_xor(ss, off);
            float nrm = sqrtf(fmaxf(ss, 1e-8f));
            float e  = __expf(nrm);
            float ei = 1.0f / e;
            float ch = 0.5f * (e + ei);
            float sh = 0.5f * (e - ei);
            kmL[w][ln] = (ln == 0) ? ch : -(sh / nrm) * spv;  // kernels*metric
        }
        __syncthreads();
        if (w == 0) {   // wave 0 builds the (shared-by-all-waves) M fragments
            const int cc = ln & 15, gg = ln >> 4;
            #pragma unroll
            for (int ks2 = 0; ks2 < 2; ++ks2) {
                bf16x8 mh, ml;
                #pragma unroll
                for (int j = 0; j < 8; ++j) {
                    float v = (cc < 8) ? kmL[cc][ks2 * 32 + gg * 8 + j] : 0.f;
                    __bf16 hh = (__bf16)v;
                    mh[j] = hh;
                    ml[j] = (__bf16)(v - (float)hh);
                }
                Mpk[(ks2 * 2 + 0) * 64 + ln] = mh;
                Mpk[(ks2 * 2 + 1) * 64 + ln] = ml;
            }
        }
        if (t < KK) esA[t] = __expf(scales[t]);
    }
}

// ---------------------------------------------------------------- pass A ---
__launch_bounds__(512)
__global__ void passA_kernel(const float* __restrict__ x,
                             const bf16x8* __restrict__ Wpk,
                             const bf16x8* __restrict__ Mpk,
                             const float* __restrict__ esA,
                             const float* __restrict__ b,
                             float* __restrict__ F) {
    __shared__ float xtr[KK][16][68];   // stride 68: write/read both 2-way (free)
    __shared__ float disl[16][12];

    const int t    = threadIdx.x;
    const int k    = t >> 6;            // wave index == kernel index
    const int lane = t & 63;
    const int c    = lane & 15;
    const int g    = lane >> 4;
    const int pbase = blockIdx.x * 16;

    // ---- prologue: PURE LOADS (all compute pre-packed by packW) ----
    bf16x8 Wh[4][2], Wl[4][2];
    #pragma unroll
    for (int nt = 0; nt < 4; ++nt)
        #pragma unroll
        for (int ks = 0; ks < 2; ++ks) {
            const size_t base = ((((size_t)k * 4 + nt) * 2 + ks) * 2) * 64 + lane;
            Wh[nt][ks] = Wpk[base];
            Wl[nt][ks] = Wpk[base + 64];
        }
    bf16x8 Mh[2], Ml[2];
    #pragma unroll
    for (int ks = 0; ks < 2; ++ks) {
        Mh[ks] = Mpk[(ks * 2 + 0) * 64 + lane];
        Ml[ks] = Mpk[(ks * 2 + 1) * 64 + lane];
    }
    const float es = esA[k];
    float bnt[4];
    #pragma unroll
    for (int nt = 0; nt < 4; ++nt) bnt[nt] = b[k * DD + nt * 16 + c];

    // ---- A fragments: this block's 16 x-rows ----
    bf16x8 Ah[2], Al[2];
    {
        const float* xr = x + (size_t)(pbase + c) * DD + g * 8;
        pack8(*(const float4*)(xr +  0), *(const float4*)(xr +  4), Ah[0], Al[0]);
        pack8(*(const float4*)(xr + 32), *(const float4*)(xr + 36), Ah[1], Al[1]);
    }

    // ---- MFMAs ----
    f32x4 accY[4];
    #pragma unroll
    for (int nt = 0; nt < 4; ++nt) accY[nt] = (f32x4){0.f, 0.f, 0.f, 0.f};
    f32x4 accI = (f32x4){0.f, 0.f, 0.f, 0.f};
    #pragma unroll
    for (int ks = 0; ks < 2; ++ks) {
        #pragma unroll
        for (int nt = 0; nt < 4; ++nt) {
            accY[nt] = MFMA16(Ah[ks], Wh[nt][ks], accY[nt]);
            accY[nt] = MFMA16(Ah[ks], Wl[nt][ks], accY[nt]);
            accY[nt] = MFMA16(Al[ks], Wh[nt][ks], accY[nt]);
        }
        accI = MFMA16(Ah[ks], Mh[ks], accI);
        accI = MFMA16(Ah[ks], Ml[ks], accI);
        accI = MFMA16(Al[ks], Mh[ks], accI);
    }

    // ---- epilogue: per-point stats (C layout: row p=g*4+rr, col o=nt*16+c) ----
    float yv[4][4], sall[4];
    #pragma unroll
    for (int rr = 0; rr < 4; ++rr) {
        float s = 0.f;
        #pragma unroll
        for (int nt = 0; nt < 4; ++nt) {
            float y = accY[nt][rr] + bnt[nt];
            yv[nt][rr] = y;
            s += y * y;
        }
        sall[rr] = s;
    }
    #pragma unroll
    for (int m = 1; m <= 8; m <<= 1)
        #pragma unroll
        for (int rr = 0; rr < 4; ++rr) sall[rr] += __shfl_xor(sall[rr], m);
    float y0[4];
    #pragma unroll
    for (int rr = 0; rr < 4; ++rr) y0[rr] = __shfl(yv[0][rr], lane & 48);

    #pragma unroll
    for (int rr = 0; rr < 4; ++rr) {
        const int p = g * 4 + rr;
        float nar2 = fmaxf(sall[rr] - y0[rr] * y0[rr], 1e-8f);
        float time = es / (1.0f + __expf(-y0[rr])) + 1.0001f;
        float s3   = sqrtf((time * time - 1.0f) / nar2);
        #pragma unroll
        for (int nt = 0; nt < 4; ++nt) {
            float v = yv[nt][rr] * s3;
            if (nt == 0 && c == 0) v = time;
            xtr[k][p][nt * 16 + c] = v;
        }
    }
    if (k == 0) {
        #pragma unroll
        for (int rr = 0; rr < 4; ++rr) {
            float nc  = fmaxf(accI[rr], 1.0f + 1e-7f);
            float dis = __logf(nc + sqrtf(nc * nc - 1.0f));  // arccosh
            if (c < 8) disl[g * 4 + rr][c] = dis;
        }
    }
    __syncthreads();

    // ---- combine: wave k handles points {2k, 2k+1} ----
    #pragma unroll
    for (int pi = 0; pi < 2; ++pi) {
        const int p = k * 2 + pi;
        float dk[KK];
        #pragma unroll
        for (int q = 0; q < KK; ++q) dk[q] = disl[p][q];
        float mx = -dk[0];
        #pragma unroll
        for (int q = 1; q < KK; ++q) mx = fmaxf(mx, -dk[q]);
        float wks[KK], sum = 0.f;
        #pragma unroll
        for (int q = 0; q < KK; ++q) { wks[q] = __expf(-dk[q] - mx); sum += wks[q]; }
        float inv = 1.0f / sum;
        float agg = 0.f;
        #pragma unroll
        for (int q = 0; q < KK; ++q) agg += wks[q] * inv * xtr[q][p][lane];

        float vv = (lane == 0) ? -agg * agg : agg * agg;
        #pragma unroll
        for (int m = 32; m > 0; m >>= 1) vv += __shfl_xor(vv, m);
        float den = sqrtf(fmaxf(fabsf(vv), 1e-8f));
        F[(size_t)(pbase + p) * DD + lane] = agg / den;
    }
}

// ---------------------------------------------------------------- pass B ---
__launch_bounds__(256)
__global__ void passB_kernel(const float* __restrict__ F,
                             const int* __restrict__ nei,
                             const int* __restrict__ mask,
                             float* __restrict__ out) {
    const int t    = threadIdx.x;
    const int wave = t >> 6;
    const int lane = t & 63;
    const int c    = lane & 15;   // col quad: o = 4c..4c+3
    const int g    = lane >> 4;   // m sub-index
    const int n    = blockIdx.x * 4 + wave;

    // one coalesced 256B fetch per wave: lanes 0..31 nei row, 32..63 mask row
    int vsrc;
    if (lane < 32) vsrc = nei[n * NNEI + lane];
    else           vsrc = mask[n * NNEI + (lane - 32)];

    const float4* F4 = (const float4*)F;
    float4 acc = {0.f, 0.f, 0.f, 0.f};
    #pragma unroll
    for (int mq = 0; mq < 8; ++mq) {
        int   m   = mq * 4 + g;
        int   j   = __shfl(vsrc, m);
        float wgt = (float)__shfl(vsrc, 32 + m) + 1e-4f;
        float4 v  = F4[(size_t)j * 16 + c];
        acc.x += wgt * v.x; acc.y += wgt * v.y;
        acc.z += wgt * v.z; acc.w += wgt * v.w;
    }
    // reduce over the 4 m-subgroups (lanes xor 16, 32)
    #pragma unroll
    for (int m = 16; m <= 32; m <<= 1) {
        acc.x += __shfl_xor(acc.x, m); acc.y += __shfl_xor(acc.y, m);
        acc.z += __shfl_xor(acc.z, m); acc.w += __shfl_xor(acc.w, m);
    }
    // lorentz inner: minus sign on o==0 (lane c==0, component .x)
    float s = acc.x * acc.x + acc.y * acc.y + acc.z * acc.z + acc.w * acc.w;
    if (c == 0) s -= 2.0f * acc.x * acc.x;
    #pragma unroll
    for (int m = 1; m <= 8; m <<= 1) s += __shfl_xor(s, m);
    float den = sqrtf(fmaxf(fabsf(s), 1e-8f));
    if (g == 0) {
        float4 rr = {acc.x / den, acc.y / den, acc.z / den, acc.w / den};
        ((float4*)out)[(size_t)n * 16 + c] = rr;
    }
}

// ---------------------------------------------------------------- launch ---
extern "C" void kernel_launch(void* const* d_in, const int* in_sizes, int n_in,
                              void* d_out, int out_size, void* d_ws, size_t ws_size,
                              hipStream_t stream) {
    const float* x      = (const float*)d_in[0];  // (12000, 64) f32
    const int*   nei    = (const int*)  d_in[1];  // (12000, 32) int32
    const int*   mask   = (const int*)  d_in[2];  // (12000, 32) int32
    const float* kp     = (const float*)d_in[3];  // (8, 64) f32
    const float* W      = (const float*)d_in[4];  // (8, 64, 64) f32
    const float* b      = (const float*)d_in[5];  // (8, 64) f32
    const float* scales = (const float*)d_in[6];  // (8,) f32
    float*       out    = (float*)d_out;          // (12000, 64) f32

    // ws: F (N*D f32) ; Wpk (8192 bf16x8 = 128KB) ; Mpk (256 bf16x8 = 4KB) ;
    //     esA (8 f32)
    const size_t needed = (size_t)(NPTS * DD) * sizeof(float)
                        + (8192 + 256) * 16 + 8 * sizeof(float);
    if (ws_size < needed) return;
    float*  F   = (float*)d_ws;
    bf16x8* Wpk = (bf16x8*)(F + (size_t)NPTS * DD);
    bf16x8* Mpk = Wpk + 8192;
    float*  esA = (float*)(Mpk + 256);

    packW_kernel<<<8, 512, 0, stream>>>(W, kp, scales, Wpk, Mpk, esA);
    passA_kernel<<<NPTS / 16, 512, 0, stream>>>(x, Wpk, Mpk, esA, b, F);
    passB_kernel<<<NPTS / 4, 256, 0, stream>>>(F, nei, mask, out);
}

// Round 11
// 31.361 us; speedup vs baseline: 15.1677x; 1.0455x over previous
//
#include <hip/hip_runtime.h>
#include <math.h>

// Problem constants: N=12000, NEI=32, K=8, D=64
#define NPTS 12000
#define NNEI 32
#define KK   8
#define DD   64

// Round 11 (from R8/R10: passA latency-bound, 88 VGPR -> 5 waves/SIMD):
//  - Drop the MFMA inner-product tile (accI): it was computed redundantly by
//    all 8 waves (identical A and M operands) and forced Mh/Ml (16 VGPR) +
//    Mpk loads + a serial wave-0-only dis section.
//  - Each wave computes its own k's inner products via a 16-FMA fp32 dot on
//    the x floats already live for pack8 + 2 shfl_xor (g-bits), then the
//    g==0 lane group does arccosh and writes disl[c][k] (distributed).
//  - packW emits plain f32 kmF (2KB) instead of M fragments.
//  - MFMA 30 -> 24, ~-20 VGPR liveness -> target 7 waves/SIMD.
//  - Grid stays 750x512 (balanced, 2.93 blocks/CU); xtr stride 68 kept.

typedef __bf16 bf16x8 __attribute__((ext_vector_type(8)));
typedef float  f32x4  __attribute__((ext_vector_type(4)));

#define MFMA16(A, B, C) __builtin_amdgcn_mfma_f32_16x16x32_bf16((A), (B), (C), 0, 0, 0)

__device__ __forceinline__ void pack8(float4 u, float4 v, bf16x8& h, bf16x8& l) {
    float a[8] = {u.x, u.y, u.z, u.w, v.x, v.y, v.z, v.w};
    #pragma unroll
    for (int i = 0; i < 8; ++i) {
        __bf16 hh = (__bf16)a[i];
        h[i] = hh;
        l[i] = (__bf16)(a[i] - (float)hh);
    }
}

__device__ __forceinline__ float dot4(float4 a, float4 b) {
    return a.x * b.x + a.y * b.y + a.z * b.z + a.w * b.w;
}

// ---------------------------------------------------------------- packW ----
// 8 blocks x 512. Block b packs W fragments for kernel k=b. Block 0 also:
// kmF[k][d] = (kernels*metric)[k][d] (f32), esA[k] = exp(scales[k]).
__launch_bounds__(512)
__global__ void packW_kernel(const float* __restrict__ W,
                             const float* __restrict__ kp,
                             const float* __restrict__ scales,
                             bf16x8* __restrict__ Wpk,
                             float*  __restrict__ kmF,
                             float*  __restrict__ esA) {
    const int t    = threadIdx.x;
    const int id   = blockIdx.x * 512 + t;   // 0..4095
    const int lane = id & 63;
    const int ks   = (id >> 6) & 1;
    const int nt   = (id >> 7) & 3;
    const int k    = id >> 9;
    const int c    = lane & 15;
    const int g    = lane >> 4;

    // ---- W fragment pack (all 8 blocks) ----
    const float* wr = W + ((size_t)k * DD + nt * 16 + c) * DD + ks * 32 + g * 8;
    bf16x8 h, l;
    pack8(*(const float4*)wr, *(const float4*)(wr + 4), h, l);
    const size_t base = ((((size_t)k * 4 + nt) * 2 + ks) * 2) * 64 + lane;
    Wpk[base]      = h;   // hi plane
    Wpk[base + 64] = l;   // lo plane

    // ---- block 0: km rows (f32) + esA ----
    if (blockIdx.x == 0) {
        const int w  = t >> 6;      // wave index = kernel row
        const int ln = t & 63;
        float spv = (ln == 0) ? 0.f : kp[w * DD + ln];   // kp[:,0]==0
        float ss = spv * spv;
        #pragma unroll
        for (int off = 32; off > 0; off >>= 1) ss += __shfl_xor(ss, off);
        float nrm = sqrtf(fmaxf(ss, 1e-8f));
        float e  = __expf(nrm);
        float ei = 1.0f / e;
        float ch = 0.5f * (e + ei);
        float sh = 0.5f * (e - ei);
        kmF[w * DD + ln] = (ln == 0) ? ch : -(sh / nrm) * spv;  // kernels*metric
        if (t < KK) esA[t] = __expf(scales[t]);
    }
}

// ---------------------------------------------------------------- pass A ---
__launch_bounds__(512)
__global__ void passA_kernel(const float* __restrict__ x,
                             const bf16x8* __restrict__ Wpk,
                             const float* __restrict__ kmF,
                             const float* __restrict__ esA,
                             const float* __restrict__ b,
                             float* __restrict__ F) {
    __shared__ float xtr[KK][16][68];   // stride 68: write/read both 2-way (free)
    __shared__ float disl[16][12];      // stride 12: 2-way write (free)

    const int t    = threadIdx.x;
    const int k    = t >> 6;            // wave index == kernel index
    const int lane = t & 63;
    const int c    = lane & 15;
    const int g    = lane >> 4;
    const int pbase = blockIdx.x * 16;

    // ---- prologue: pure loads ----
    bf16x8 Wh[4][2], Wl[4][2];
    #pragma unroll
    for (int nt = 0; nt < 4; ++nt)
        #pragma unroll
        for (int ks = 0; ks < 2; ++ks) {
            const size_t base = ((((size_t)k * 4 + nt) * 2 + ks) * 2) * 64 + lane;
            Wh[nt][ks] = Wpk[base];
            Wl[nt][ks] = Wpk[base + 64];
        }
    const float es = esA[k];
    float bnt[4];
    #pragma unroll
    for (int nt = 0; nt < 4; ++nt) bnt[nt] = b[k * DD + nt * 16 + c];

    // ---- x row chunks (16 floats, kept live for dot + pack) ----
    float4 u0, u1, u2, u3;
    {
        const float* xr = x + (size_t)(pbase + c) * DD + g * 8;
        u0 = *(const float4*)(xr +  0);
        u1 = *(const float4*)(xr +  4);
        u2 = *(const float4*)(xr + 32);
        u3 = *(const float4*)(xr + 36);
    }

    // ---- inner product <x_row, km_k> via fp32 dot (replaces accI MFMAs) ----
    {
        const float4* km4 = (const float4*)(kmF + k * DD);
        float ip = dot4(u0, km4[g * 2 + 0]) + dot4(u1, km4[g * 2 + 1])
                 + dot4(u2, km4[g * 2 + 8]) + dot4(u3, km4[g * 2 + 9]);
        ip += __shfl_xor(ip, 16);
        ip += __shfl_xor(ip, 32);   // all 4 g-groups summed; lanes with same c agree
        if (g == 0) {
            float nc  = fmaxf(ip, 1.0f + 1e-7f);
            float dis = __logf(nc + sqrtf(nc * nc - 1.0f));  // arccosh
            disl[c][k] = dis;
        }
    }

    // ---- A fragments ----
    bf16x8 Ah[2], Al[2];
    pack8(u0, u1, Ah[0], Al[0]);
    pack8(u2, u3, Ah[1], Al[1]);

    // ---- MFMAs: Y only (24) ----
    f32x4 accY[4];
    #pragma unroll
    for (int nt = 0; nt < 4; ++nt) accY[nt] = (f32x4){0.f, 0.f, 0.f, 0.f};
    #pragma unroll
    for (int ks = 0; ks < 2; ++ks)
        #pragma unroll
        for (int nt = 0; nt < 4; ++nt) {
            accY[nt] = MFMA16(Ah[ks], Wh[nt][ks], accY[nt]);
            accY[nt] = MFMA16(Ah[ks], Wl[nt][ks], accY[nt]);
            accY[nt] = MFMA16(Al[ks], Wh[nt][ks], accY[nt]);
        }

    // ---- epilogue: per-point stats (C layout: row p=g*4+rr, col o=nt*16+c) ----
    float yv[4][4], sall[4];
    #pragma unroll
    for (int rr = 0; rr < 4; ++rr) {
        float s = 0.f;
        #pragma unroll
        for (int nt = 0; nt < 4; ++nt) {
            float y = accY[nt][rr] + bnt[nt];
            yv[nt][rr] = y;
            s += y * y;
        }
        sall[rr] = s;
    }
    #pragma unroll
    for (int m = 1; m <= 8; m <<= 1)
        #pragma unroll
        for (int rr = 0; rr < 4; ++rr) sall[rr] += __shfl_xor(sall[rr], m);
    float y0[4];
    #pragma unroll
    for (int rr = 0; rr < 4; ++rr) y0[rr] = __shfl(yv[0][rr], lane & 48);

    #pragma unroll
    for (int rr = 0; rr < 4; ++rr) {
        const int p = g * 4 + rr;
        float nar2 = fmaxf(sall[rr] - y0[rr] * y0[rr], 1e-8f);
        float time = es / (1.0f + __expf(-y0[rr])) + 1.0001f;
        float s3   = sqrtf((time * time - 1.0f) / nar2);
        #pragma unroll
        for (int nt = 0; nt < 4; ++nt) {
            float v = yv[nt][rr] * s3;
            if (nt == 0 && c == 0) v = time;
            xtr[k][p][nt * 16 + c] = v;
        }
    }
    __syncthreads();

    // ---- combine: wave k handles points {2k, 2k+1} ----
    #pragma unroll
    for (int pi = 0; pi < 2; ++pi) {
        const int p = k * 2 + pi;
        float dk[KK];
        #pragma unroll
        for (int q = 0; q < KK; ++q) dk[q] = disl[p][q];   // broadcast reads
        float mx = -dk[0];
        #pragma unroll
        for (int q = 1; q < KK; ++q) mx = fmaxf(mx, -dk[q]);
        float wks[KK], sum = 0.f;
        #pragma unroll
        for (int q = 0; q < KK; ++q) { wks[q] = __expf(-dk[q] - mx); sum += wks[q]; }
        float inv = 1.0f / sum;
        float agg = 0.f;
        #pragma unroll
        for (int q = 0; q < KK; ++q) agg += wks[q] * inv * xtr[q][p][lane];

        float vv = (lane == 0) ? -agg * agg : agg * agg;
        #pragma unroll
        for (int m = 32; m > 0; m >>= 1) vv += __shfl_xor(vv, m);
        float den = sqrtf(fmaxf(fabsf(vv), 1e-8f));
        F[(size_t)(pbase + p) * DD + lane] = agg / den;
    }
}

// ---------------------------------------------------------------- pass B ---
__launch_bounds__(256)
__global__ void passB_kernel(const float* __restrict__ F,
                             const int* __restrict__ nei,
                             const int* __restrict__ mask,
                             float* __restrict__ out) {
    const int t    = threadIdx.x;
    const int wave = t >> 6;
    const int lane = t & 63;
    const int c    = lane & 15;   // col quad: o = 4c..4c+3
    const int g    = lane >> 4;   // m sub-index
    const int n    = blockIdx.x * 4 + wave;

    // one coalesced 256B fetch per wave: lanes 0..31 nei row, 32..63 mask row
    int vsrc;
    if (lane < 32) vsrc = nei[n * NNEI + lane];
    else           vsrc = mask[n * NNEI + (lane - 32)];

    const float4* F4 = (const float4*)F;
    float4 acc = {0.f, 0.f, 0.f, 0.f};
    #pragma unroll
    for (int mq = 0; mq < 8; ++mq) {
        int   m   = mq * 4 + g;
        int   j   = __shfl(vsrc, m);
        float wgt = (float)__shfl(vsrc, 32 + m) + 1e-4f;
        float4 v  = F4[(size_t)j * 16 + c];
        acc.x += wgt * v.x; acc.y += wgt * v.y;
        acc.z += wgt * v.z; acc.w += wgt * v.w;
    }
    // reduce over the 4 m-subgroups (lanes xor 16, 32)
    #pragma unroll
    for (int m = 16; m <= 32; m <<= 1) {
        acc.x += __shfl_xor(acc.x, m); acc.y += __shfl_xor(acc.y, m);
        acc.z += __shfl_xor(acc.z, m); acc.w += __shfl_xor(acc.w, m);
    }
    // lorentz inner: minus sign on o==0 (lane c==0, component .x)
    float s = acc.x * acc.x + acc.y * acc.y + acc.z * acc.z + acc.w * acc.w;
    if (c == 0) s -= 2.0f * acc.x * acc.x;
    #pragma unroll
    for (int m = 1; m <= 8; m <<= 1) s += __shfl_xor(s, m);
    float den = sqrtf(fmaxf(fabsf(s), 1e-8f));
    if (g == 0) {
        float4 rr = {acc.x / den, acc.y / den, acc.z / den, acc.w / den};
        ((float4*)out)[(size_t)n * 16 + c] = rr;
    }
}

// ---------------------------------------------------------------- launch ---
extern "C" void kernel_launch(void* const* d_in, const int* in_sizes, int n_in,
                              void* d_out, int out_size, void* d_ws, size_t ws_size,
                              hipStream_t stream) {
    const float* x      = (const float*)d_in[0];  // (12000, 64) f32
    const int*   nei    = (const int*)  d_in[1];  // (12000, 32) int32
    const int*   mask   = (const int*)  d_in[2];  // (12000, 32) int32
    const float* kp     = (const float*)d_in[3];  // (8, 64) f32
    const float* W      = (const float*)d_in[4];  // (8, 64, 64) f32
    const float* b      = (const float*)d_in[5];  // (8, 64) f32
    const float* scales = (const float*)d_in[6];  // (8,) f32
    float*       out    = (float*)d_out;          // (12000, 64) f32

    // ws: F (N*D f32) ; Wpk (8192 bf16x8 = 128KB) ; kmF (512 f32) ; esA (8 f32)
    const size_t needed = (size_t)(NPTS * DD) * sizeof(float)
                        + 8192 * 16 + (512 + 8) * sizeof(float);
    if (ws_size < needed) return;
    float*  F   = (float*)d_ws;
    bf16x8* Wpk = (bf16x8*)(F + (size_t)NPTS * DD);
    float*  kmF = (float*)(Wpk + 8192);
    float*  esA = kmF + 512;

    packW_kernel<<<8, 512, 0, stream>>>(W, kp, scales, Wpk, kmF, esA);
    passA_kernel<<<NPTS / 16, 512, 0, stream>>>(x, Wpk, kmF, esA, b, F);
    passB_kernel<<<NPTS / 4, 256, 0, stream>>>(F, nei, mask, out);
}

// Round 12
// 30.674 us; speedup vs baseline: 15.5073x; 1.0224x over previous
//
#include <hip/hip_runtime.h>
#include <math.h>

// Problem constants: N=12000, NEI=32, K=8, D=64
#define NPTS 12000
#define NNEI 32
#define KK   8
#define DD   64

// Round 12 (= R11 + exact softmax algebra):
//   dis = arccosh(nc) = log(z), z = nc + sqrt(nc^2-1)
//   softmax(-dis)_k = exp(-dis_k)/sum = (1/z_k)/sum_q(1/z_q)   EXACTLY.
//   -> delete 8 __logf (dis) and 8 __expf + max-chain (combine) from the
//      per-wave critical path; disl stores u = 1/z directly.
// Everything else identical to R11 (750x512 balanced grid, pre-packed Wpk,
// fp32 dot for inner products, stride-68 xtr, coalesced passB).

typedef __bf16 bf16x8 __attribute__((ext_vector_type(8)));
typedef float  f32x4  __attribute__((ext_vector_type(4)));

#define MFMA16(A, B, C) __builtin_amdgcn_mfma_f32_16x16x32_bf16((A), (B), (C), 0, 0, 0)

__device__ __forceinline__ void pack8(float4 u, float4 v, bf16x8& h, bf16x8& l) {
    float a[8] = {u.x, u.y, u.z, u.w, v.x, v.y, v.z, v.w};
    #pragma unroll
    for (int i = 0; i < 8; ++i) {
        __bf16 hh = (__bf16)a[i];
        h[i] = hh;
        l[i] = (__bf16)(a[i] - (float)hh);
    }
}

__device__ __forceinline__ float dot4(float4 a, float4 b) {
    return a.x * b.x + a.y * b.y + a.z * b.z + a.w * b.w;
}

// ---------------------------------------------------------------- packW ----
// 8 blocks x 512. Block b packs W fragments for kernel k=b. Block 0 also:
// kmF[k][d] = (kernels*metric)[k][d] (f32), esA[k] = exp(scales[k]).
__launch_bounds__(512)
__global__ void packW_kernel(const float* __restrict__ W,
                             const float* __restrict__ kp,
                             const float* __restrict__ scales,
                             bf16x8* __restrict__ Wpk,
                             float*  __restrict__ kmF,
                             float*  __restrict__ esA) {
    const int t    = threadIdx.x;
    const int id   = blockIdx.x * 512 + t;   // 0..4095
    const int lane = id & 63;
    const int ks   = (id >> 6) & 1;
    const int nt   = (id >> 7) & 3;
    const int k    = id >> 9;
    const int c    = lane & 15;
    const int g    = lane >> 4;

    // ---- W fragment pack (all 8 blocks) ----
    const float* wr = W + ((size_t)k * DD + nt * 16 + c) * DD + ks * 32 + g * 8;
    bf16x8 h, l;
    pack8(*(const float4*)wr, *(const float4*)(wr + 4), h, l);
    const size_t base = ((((size_t)k * 4 + nt) * 2 + ks) * 2) * 64 + lane;
    Wpk[base]      = h;   // hi plane
    Wpk[base + 64] = l;   // lo plane

    // ---- block 0: km rows (f32) + esA ----
    if (blockIdx.x == 0) {
        const int w  = t >> 6;      // wave index = kernel row
        const int ln = t & 63;
        float spv = (ln == 0) ? 0.f : kp[w * DD + ln];   // kp[:,0]==0
        float ss = spv * spv;
        #pragma unroll
        for (int off = 32; off > 0; off >>= 1) ss += __shfl_xor(ss, off);
        float nrm = sqrtf(fmaxf(ss, 1e-8f));
        float e  = __expf(nrm);
        float ei = 1.0f / e;
        float ch = 0.5f * (e + ei);
        float sh = 0.5f * (e - ei);
        kmF[w * DD + ln] = (ln == 0) ? ch : -(sh / nrm) * spv;  // kernels*metric
        if (t < KK) esA[t] = __expf(scales[t]);
    }
}

// ---------------------------------------------------------------- pass A ---
__launch_bounds__(512)
__global__ void passA_kernel(const float* __restrict__ x,
                             const bf16x8* __restrict__ Wpk,
                             const float* __restrict__ kmF,
                             const float* __restrict__ esA,
                             const float* __restrict__ b,
                             float* __restrict__ F) {
    __shared__ float xtr[KK][16][68];   // stride 68: write/read both 2-way (free)
    __shared__ float disl[16][12];      // holds u = 1/z per (point, k)

    const int t    = threadIdx.x;
    const int k    = t >> 6;            // wave index == kernel index
    const int lane = t & 63;
    const int c    = lane & 15;
    const int g    = lane >> 4;
    const int pbase = blockIdx.x * 16;

    // ---- prologue: pure loads ----
    bf16x8 Wh[4][2], Wl[4][2];
    #pragma unroll
    for (int nt = 0; nt < 4; ++nt)
        #pragma unroll
        for (int ks = 0; ks < 2; ++ks) {
            const size_t base = ((((size_t)k * 4 + nt) * 2 + ks) * 2) * 64 + lane;
            Wh[nt][ks] = Wpk[base];
            Wl[nt][ks] = Wpk[base + 64];
        }
    const float es = esA[k];
    float bnt[4];
    #pragma unroll
    for (int nt = 0; nt < 4; ++nt) bnt[nt] = b[k * DD + nt * 16 + c];

    // ---- x row chunks (16 floats, kept live for dot + pack) ----
    float4 u0, u1, u2, u3;
    {
        const float* xr = x + (size_t)(pbase + c) * DD + g * 8;
        u0 = *(const float4*)(xr +  0);
        u1 = *(const float4*)(xr +  4);
        u2 = *(const float4*)(xr + 32);
        u3 = *(const float4*)(xr + 36);
    }

    // ---- inner product <x_row, km_k>; softmax numerator u = 1/z (exact) ----
    {
        const float4* km4 = (const float4*)(kmF + k * DD);
        float ip = dot4(u0, km4[g * 2 + 0]) + dot4(u1, km4[g * 2 + 1])
                 + dot4(u2, km4[g * 2 + 8]) + dot4(u3, km4[g * 2 + 9]);
        ip += __shfl_xor(ip, 16);
        ip += __shfl_xor(ip, 32);   // all 4 g-groups summed; lanes with same c agree
        if (g == 0) {
            float nc = fmaxf(ip, 1.0f + 1e-7f);
            // exp(-arccosh(nc)) = 1 / (nc + sqrt(nc^2 - 1))  -- exact
            disl[c][k] = 1.0f / (nc + sqrtf(nc * nc - 1.0f));
        }
    }

    // ---- A fragments ----
    bf16x8 Ah[2], Al[2];
    pack8(u0, u1, Ah[0], Al[0]);
    pack8(u2, u3, Ah[1], Al[1]);

    // ---- MFMAs: Y only (24) ----
    f32x4 accY[4];
    #pragma unroll
    for (int nt = 0; nt < 4; ++nt) accY[nt] = (f32x4){0.f, 0.f, 0.f, 0.f};
    #pragma unroll
    for (int ks = 0; ks < 2; ++ks)
        #pragma unroll
        for (int nt = 0; nt < 4; ++nt) {
            accY[nt] = MFMA16(Ah[ks], Wh[nt][ks], accY[nt]);
            accY[nt] = MFMA16(Ah[ks], Wl[nt][ks], accY[nt]);
            accY[nt] = MFMA16(Al[ks], Wh[nt][ks], accY[nt]);
        }

    // ---- epilogue: per-point stats (C layout: row p=g*4+rr, col o=nt*16+c) ----
    float yv[4][4], sall[4];
    #pragma unroll
    for (int rr = 0; rr < 4; ++rr) {
        float s = 0.f;
        #pragma unroll
        for (int nt = 0; nt < 4; ++nt) {
            float y = accY[nt][rr] + bnt[nt];
            yv[nt][rr] = y;
            s += y * y;
        }
        sall[rr] = s;
    }
    #pragma unroll
    for (int m = 1; m <= 8; m <<= 1)
        #pragma unroll
        for (int rr = 0; rr < 4; ++rr) sall[rr] += __shfl_xor(sall[rr], m);
    float y0[4];
    #pragma unroll
    for (int rr = 0; rr < 4; ++rr) y0[rr] = __shfl(yv[0][rr], lane & 48);

    #pragma unroll
    for (int rr = 0; rr < 4; ++rr) {
        const int p = g * 4 + rr;
        float nar2 = fmaxf(sall[rr] - y0[rr] * y0[rr], 1e-8f);
        float time = es / (1.0f + __expf(-y0[rr])) + 1.0001f;
        float s3   = sqrtf((time * time - 1.0f) / nar2);
        #pragma unroll
        for (int nt = 0; nt < 4; ++nt) {
            float v = yv[nt][rr] * s3;
            if (nt == 0 && c == 0) v = time;
            xtr[k][p][nt * 16 + c] = v;
        }
    }
    __syncthreads();

    // ---- combine: wave k handles points {2k, 2k+1} ----
    #pragma unroll
    for (int pi = 0; pi < 2; ++pi) {
        const int p = k * 2 + pi;
        float uk[KK];
        float sum = 0.f;
        #pragma unroll
        for (int q = 0; q < KK; ++q) { uk[q] = disl[p][q]; sum += uk[q]; }
        float inv = 1.0f / sum;
        float agg = 0.f;
        #pragma unroll
        for (int q = 0; q < KK; ++q) agg += uk[q] * inv * xtr[q][p][lane];

        float vv = (lane == 0) ? -agg * agg : agg * agg;
        #pragma unroll
        for (int m = 32; m > 0; m >>= 1) vv += __shfl_xor(vv, m);
        float den = sqrtf(fmaxf(fabsf(vv), 1e-8f));
        F[(size_t)(pbase + p) * DD + lane] = agg / den;
    }
}

// ---------------------------------------------------------------- pass B ---
__launch_bounds__(256)
__global__ void passB_kernel(const float* __restrict__ F,
                             const int* __restrict__ nei,
                             const int* __restrict__ mask,
                             float* __restrict__ out) {
    const int t    = threadIdx.x;
    const int wave = t >> 6;
    const int lane = t & 63;
    const int c    = lane & 15;   // col quad: o = 4c..4c+3
    const int g    = lane >> 4;   // m sub-index
    const int n    = blockIdx.x * 4 + wave;

    // one coalesced 256B fetch per wave: lanes 0..31 nei row, 32..63 mask row
    int vsrc;
    if (lane < 32) vsrc = nei[n * NNEI + lane];
    else           vsrc = mask[n * NNEI + (lane - 32)];

    const float4* F4 = (const float4*)F;
    float4 acc = {0.f, 0.f, 0.f, 0.f};
    #pragma unroll
    for (int mq = 0; mq < 8; ++mq) {
        int   m   = mq * 4 + g;
        int   j   = __shfl(vsrc, m);
        float wgt = (float)__shfl(vsrc, 32 + m) + 1e-4f;
        float4 v  = F4[(size_t)j * 16 + c];
        acc.x += wgt * v.x; acc.y += wgt * v.y;
        acc.z += wgt * v.z; acc.w += wgt * v.w;
    }
    // reduce over the 4 m-subgroups (lanes xor 16, 32)
    #pragma unroll
    for (int m = 16; m <= 32; m <<= 1) {
        acc.x += __shfl_xor(acc.x, m); acc.y += __shfl_xor(acc.y, m);
        acc.z += __shfl_xor(acc.z, m); acc.w += __shfl_xor(acc.w, m);
    }
    // lorentz inner: minus sign on o==0 (lane c==0, component .x)
    float s = acc.x * acc.x + acc.y * acc.y + acc.z * acc.z + acc.w * acc.w;
    if (c == 0) s -= 2.0f * acc.x * acc.x;
    #pragma unroll
    for (int m = 1; m <= 8; m <<= 1) s += __shfl_xor(s, m);
    float den = sqrtf(fmaxf(fabsf(s), 1e-8f));
    if (g == 0) {
        float4 rr = {acc.x / den, acc.y / den, acc.z / den, acc.w / den};
        ((float4*)out)[(size_t)n * 16 + c] = rr;
    }
}

// ---------------------------------------------------------------- launch ---
extern "C" void kernel_launch(void* const* d_in, const int* in_sizes, int n_in,
                              void* d_out, int out_size, void* d_ws, size_t ws_size,
                              hipStream_t stream) {
    const float* x      = (const float*)d_in[0];  // (12000, 64) f32
    const int*   nei    = (const int*)  d_in[1];  // (12000, 32) int32
    const int*   mask   = (const int*)  d_in[2];  // (12000, 32) int32
    const float* kp     = (const float*)d_in[3];  // (8, 64) f32
    const float* W      = (const float*)d_in[4];  // (8, 64, 64) f32
    const float* b      = (const float*)d_in[5];  // (8, 64) f32
    const float* scales = (const float*)d_in[6];  // (8,) f32
    float*       out    = (float*)d_out;          // (12000, 64) f32

    // ws: F (N*D f32) ; Wpk (8192 bf16x8 = 128KB) ; kmF (512 f32) ; esA (8 f32)
    const size_t needed = (size_t)(NPTS * DD) * sizeof(float)
                        + 8192 * 16 + (512 + 8) * sizeof(float);
    if (ws_size < needed) return;
    float*  F   = (float*)d_ws;
    bf16x8* Wpk = (bf16x8*)(F + (size_t)NPTS * DD);
    float*  kmF = (float*)(Wpk + 8192);
    float*  esA = kmF + 512;

    packW_kernel<<<8, 512, 0, stream>>>(W, kp, scales, Wpk, kmF, esA);
    passA_kernel<<<NPTS / 16, 512, 0, stream>>>(x, Wpk, kmF, esA, b, F);
    passB_kernel<<<NPTS / 4, 256, 0, stream>>>(F, nei, mask, out);
}